// Round 1
// baseline (1025.719 us; speedup 1.0000x reference)
//
#include <hip/hip_runtime.h>
#include <stdint.h>

typedef __attribute__((ext_vector_type(4))) float f32x4;
typedef __attribute__((ext_vector_type(8))) __bf16 bf16x8;

#define DEV __device__ __forceinline__

DEV ushort f2bf(float f) {
  union { float f; uint32_t u; } v; v.f = f;
  uint32_t u = v.u;
  return (ushort)((u + 0x7FFFu + ((u >> 16) & 1u)) >> 16);  // RTNE
}
DEV float bf2f(ushort h) {
  union { uint32_t u; float f; } v; v.u = ((uint32_t)h) << 16;
  return v.f;
}
// async global->LDS, 16B per lane. gptr is PER-LANE, lds base must be wave-uniform.
DEV void async16(void* lds, const void* g) {
  __builtin_amdgcn_global_load_lds((const __attribute__((address_space(1))) void*)g,
                                   (__attribute__((address_space(3))) void*)lds, 16, 0, 0);
}

#define B_  2048
#define R_  39200
#define F_  512
#define S_  64
#define H_  512
#define G_  256
#define E_  32
#define MH_ 512
#define A_  7
#define KSLICES 7
#define KSLICE_LEN 5600   // 39200/7, = 175*32

// ---------------- convert fp32 -> bf16 (vectorized) ----------------
__global__ void convert_bf16_kernel(const float* __restrict__ in, ushort* __restrict__ out, long n4) {
  long i = (long)blockIdx.x * blockDim.x + threadIdx.x;
  long stride = (long)gridDim.x * blockDim.x;
  const float4* in4 = (const float4*)in;
  ushort4* out4 = (ushort4*)out;
  for (; i < n4; i += stride) {
    float4 f = in4[i];
    ushort4 o;
    o.x = f2bf(f.x); o.y = f2bf(f.y); o.z = f2bf(f.z); o.w = f2bf(f.w);
    out4[i] = o;
  }
}

// ---------------- transpose + convert: in [z][R][C] f32 -> out [z][C][R] bf16 ----------------
__global__ void transpose_bf16_kernel(const float* __restrict__ in, ushort* __restrict__ out,
                                      int R, int C) {
  __shared__ float tile[32][33];
  size_t bo = (size_t)blockIdx.z * R * C;
  in += bo; out += bo;
  int c0 = blockIdx.x * 32, r0 = blockIdx.y * 32;
  int tx = threadIdx.x, ty = threadIdx.y;
#pragma unroll
  for (int i = 0; i < 4; i++)
    tile[ty + i*8][tx] = in[(size_t)(r0 + ty + i*8) * C + c0 + tx];
  __syncthreads();
#pragma unroll
  for (int i = 0; i < 4; i++)
    out[(size_t)(c0 + ty + i*8) * R + r0 + tx] = f2bf(tile[tx][ty + i*8]);
}

// ---------------- trunk GEMM: A[2048,39200]bf16 @ Bt[512,39200]bf16 -> partials[slice][2048][512] f32
// 128x128 tile, BK=32, 256 thr (4 waves 2x2, wave-tile 64x64, 4x4 mfma accs)
__global__ __launch_bounds__(256)
void gemm_trunk_kernel(const ushort* __restrict__ A, const ushort* __restrict__ Bt,
                       float* __restrict__ Cp) {
  __shared__ __align__(16) ushort As[128 * 32];
  __shared__ __align__(16) ushort Bs[128 * 32];
  const int tid = threadIdx.x;
  const int w = tid >> 6, l = tid & 63;
  const int wm = w >> 1, wn = w & 1;
  const int lrow = l & 15, lq = l >> 4;
  const int mb = blockIdx.x >> 2, nb = blockIdx.x & 3;
  const int ks = blockIdx.y * KSLICE_LEN;
  f32x4 acc[4][4] = {};
  const int srow = tid >> 2;
  const int scol = (tid & 3) * 8;
  const ushort* Ab = A + (size_t)(mb * 128 + srow) * R_ + scol;
  const ushort* Bb = Bt + (size_t)(nb * 128 + srow) * R_ + scol;
  char* AsB = (char*)As + w * 1024;
  char* BsB = (char*)Bs + w * 1024;
  for (int k0 = ks; k0 < ks + KSLICE_LEN; k0 += 32) {
    async16(AsB,        Ab + k0);
    async16(AsB + 4096, Ab + (size_t)64 * R_ + k0);
    async16(BsB,        Bb + k0);
    async16(BsB + 4096, Bb + (size_t)64 * R_ + k0);
    __syncthreads();
    bf16x8 af[4], bfr[4];
#pragma unroll
    for (int i = 0; i < 4; i++)
      af[i] = *(const bf16x8*)(As + (wm * 64 + i * 16 + lrow) * 32 + lq * 8);
#pragma unroll
    for (int i = 0; i < 4; i++)
      bfr[i] = *(const bf16x8*)(Bs + (wn * 64 + i * 16 + lrow) * 32 + lq * 8);
#pragma unroll
    for (int mi = 0; mi < 4; mi++)
#pragma unroll
      for (int ni = 0; ni < 4; ni++)
        acc[mi][ni] = __builtin_amdgcn_mfma_f32_16x16x32_bf16(af[mi], bfr[ni], acc[mi][ni], 0, 0, 0);
    __syncthreads();
  }
  float* C = Cp + (size_t)blockIdx.y * B_ * F_;
#pragma unroll
  for (int mi = 0; mi < 4; mi++)
#pragma unroll
    for (int ni = 0; ni < 4; ni++) {
      int col = nb * 128 + wn * 64 + ni * 16 + lrow;
#pragma unroll
      for (int r = 0; r < 4; r++) {
        int row = mb * 128 + wm * 64 + mi * 16 + lq * 4 + r;
        C[(size_t)row * F_ + col] = acc[mi][ni][r];
      }
    }
}

// ---------------- generic 128x128 GEMM, packed A[M,K] bf16 @ Bt[N,K] bf16, bias+relu -> bf16 out
__global__ __launch_bounds__(256)
void gemm_brelu_kernel(const ushort* __restrict__ A, const ushort* __restrict__ Bt,
                       const float* __restrict__ bias, ushort* __restrict__ out,
                       int K, int N, int nTiles) {
  __shared__ __align__(16) ushort As[128 * 32];
  __shared__ __align__(16) ushort Bs[128 * 32];
  const int tid = threadIdx.x;
  const int w = tid >> 6, l = tid & 63;
  const int wm = w >> 1, wn = w & 1;
  const int lrow = l & 15, lq = l >> 4;
  const int mb = blockIdx.x / nTiles, nb = blockIdx.x % nTiles;
  f32x4 acc[4][4] = {};
  const int srow = tid >> 2;
  const int scol = (tid & 3) * 8;
  const ushort* Ab = A + (size_t)(mb * 128 + srow) * K + scol;
  const ushort* Bb = Bt + (size_t)(nb * 128 + srow) * K + scol;
  char* AsB = (char*)As + w * 1024;
  char* BsB = (char*)Bs + w * 1024;
  for (int k0 = 0; k0 < K; k0 += 32) {
    async16(AsB,        Ab + k0);
    async16(AsB + 4096, Ab + (size_t)64 * K + k0);
    async16(BsB,        Bb + k0);
    async16(BsB + 4096, Bb + (size_t)64 * K + k0);
    __syncthreads();
    bf16x8 af[4], bfr[4];
#pragma unroll
    for (int i = 0; i < 4; i++)
      af[i] = *(const bf16x8*)(As + (wm * 64 + i * 16 + lrow) * 32 + lq * 8);
#pragma unroll
    for (int i = 0; i < 4; i++)
      bfr[i] = *(const bf16x8*)(Bs + (wn * 64 + i * 16 + lrow) * 32 + lq * 8);
#pragma unroll
    for (int mi = 0; mi < 4; mi++)
#pragma unroll
      for (int ni = 0; ni < 4; ni++)
        acc[mi][ni] = __builtin_amdgcn_mfma_f32_16x16x32_bf16(af[mi], bfr[ni], acc[mi][ni], 0, 0, 0);
    __syncthreads();
  }
#pragma unroll
  for (int mi = 0; mi < 4; mi++)
#pragma unroll
    for (int ni = 0; ni < 4; ni++) {
      int col = nb * 128 + wn * 64 + ni * 16 + lrow;
      float bv = bias[col];
#pragma unroll
      for (int r = 0; r < 4; r++) {
        int row = mb * 128 + wm * 64 + mi * 16 + lq * 4 + r;
        out[(size_t)row * N + col] = f2bf(fmaxf(acc[mi][ni][r] + bv, 0.f));
      }
    }
}

// ---------------- reduce split-K partials + bias + LayerNorm + tanh + sensor concat ----------------
__global__ void reduce_ln_kernel(const float* __restrict__ Cp, const float* __restrict__ tb,
                                 const float* __restrict__ g, const float* __restrict__ bb,
                                 const float* __restrict__ sensor, ushort* __restrict__ xcat) {
  int row = blockIdx.x, tid = threadIdx.x;
  const float* base = Cp + (size_t)row * F_;
  float v0 = tb[tid], v1 = tb[tid + 256];
#pragma unroll
  for (int s = 0; s < KSLICES; s++) {
    v0 += base[(size_t)s * B_ * F_ + tid];
    v1 += base[(size_t)s * B_ * F_ + tid + 256];
  }
  float s1 = v0 + v1, s2 = v0 * v0 + v1 * v1;
  for (int o = 32; o; o >>= 1) { s1 += __shfl_down(s1, o); s2 += __shfl_down(s2, o); }
  __shared__ float r1[4], r2[4];
  __shared__ float mus, rss;
  if ((tid & 63) == 0) { r1[tid >> 6] = s1; r2[tid >> 6] = s2; }
  __syncthreads();
  if (tid == 0) {
    float a = r1[0] + r1[1] + r1[2] + r1[3];
    float q = r2[0] + r2[1] + r2[2] + r2[3];
    float mu = a * (1.0f / F_);
    float var = q * (1.0f / F_) - mu * mu;
    mus = mu; rss = rsqrtf(var + 1e-5f);
  }
  __syncthreads();
  float mu = mus, rs = rss;
  ushort* xr = xcat + (size_t)row * (F_ + S_);
  xr[tid]       = f2bf(tanhf((v0 - mu) * rs * g[tid] + bb[tid]));
  xr[tid + 256] = f2bf(tanhf((v1 - mu) * rs * g[tid + 256] + bb[tid + 256]));
  if (tid < S_) xr[F_ + tid] = f2bf(sensor[(size_t)row * S_ + tid]);
}

// ---------------- gate layer2 + softmax + top4 + counts/density atomics ----------------
__global__ void gate_topk_kernel(const ushort* __restrict__ tbuf, const float* __restrict__ w2,
                                 const float* __restrict__ b2, float* __restrict__ gate_w,
                                 int* __restrict__ gate_i, float* __restrict__ density,
                                 int* __restrict__ counts) {
  int row = blockIdx.x, tid = threadIdx.x;
  int jj = tid >> 5, e = tid & 31;
  const ushort* tr = tbuf + (size_t)row * G_;
  float s = 0;
  int k0 = jj * 32;
#pragma unroll
  for (int k = 0; k < 32; k++) s += bf2f(tr[k0 + k]) * w2[(size_t)(k0 + k) * E_ + e];
  __shared__ float part[8][32];
  part[jj][e] = s;
  __syncthreads();
  if (tid < 32) {
    float logit = b2[tid];
#pragma unroll
    for (int j = 0; j < 8; j++) logit += part[j][tid];
    float m = logit;
    for (int o = 16; o; o >>= 1) m = fmaxf(m, __shfl_xor(m, o));
    float p = expf(logit - m);
    float sum = p;
    for (int o = 16; o; o >>= 1) sum += __shfl_xor(sum, o);
    float prob = p / sum;
    bool sel = false;
    float tv[4]; int ti[4];
#pragma unroll
    for (int it = 0; it < 4; it++) {
      float c = sel ? -1.0f : prob;
      float mx = c;
      for (int o = 16; o; o >>= 1) mx = fmaxf(mx, __shfl_xor(mx, o));
      unsigned long long bal = __ballot(c == mx);
      int idx = __ffsll(bal) - 1;
      if (tid == idx) sel = true;
      tv[it] = mx; ti[it] = idx;
    }
    float wsum = tv[0] + tv[1] + tv[2] + tv[3];
#pragma unroll
    for (int it = 0; it < 4; it++)
      if (tid == it) { gate_w[row * 4 + it] = tv[it] / wsum; gate_i[row * 4 + it] = ti[it]; }
    atomicAdd(&density[tid], prob);
    if (sel) atomicAdd(&counts[tid], 1);
  }
}

// ---------------- exclusive scan of counts + aux loss ----------------
__global__ void scan_aux_kernel(const int* __restrict__ counts, const float* __restrict__ density,
                                int* __restrict__ offsets, float* __restrict__ aux_out) {
  if (threadIdx.x == 0) {
    int acc = 0; float a = 0;
    for (int e = 0; e < E_; e++) {
      offsets[e] = acc; acc += counts[e];
      a += (float)counts[e] * density[e];
    }
    aux_out[0] = (float)E_ * a / ((float)B_ * (float)B_);
  }
}

// ---------------- bucket rows by expert ----------------
__global__ void fill_slots_kernel(const int* __restrict__ gate_i, const float* __restrict__ gate_w,
                                  const int* __restrict__ offsets, int* __restrict__ cursors,
                                  int* __restrict__ slot_row, float* __restrict__ slot_w) {
  int r = blockIdx.x * blockDim.x + threadIdx.x;
  if (r >= B_) return;
  for (int k = 0; k < 4; k++) {
    int e = gate_i[r * 4 + k];
    int pos = atomicAdd(&cursors[e], 1);
    int s = offsets[e] + pos;
    slot_row[s] = r;
    slot_w[s] = gate_w[r * 4 + k];
  }
}

// ---------------- expert GEMM1: hid = relu(x[slot_row] @ e_w1[e] + b1) ----------------
// tile 64x128, BK=32, 256 thr (waves 2x2; wave-tile 32x64, 2x4 accs)
__global__ __launch_bounds__(256)
void expert1_kernel(const ushort* __restrict__ x, const ushort* __restrict__ w1T,
                    const float* __restrict__ b1, const int* __restrict__ counts,
                    const int* __restrict__ offsets, const int* __restrict__ slot_row,
                    ushort* __restrict__ hid) {
  const int e = blockIdx.z, nb = blockIdx.y, cx = blockIdx.x;
  const int cnt = counts[e];
  if (cnt == 0) return;
  const int off = offsets[e];
  __shared__ __align__(16) ushort As[64 * 32];
  __shared__ __align__(16) ushort Bs[128 * 32];
  const int tid = threadIdx.x;
  const int w = tid >> 6, l = tid & 63;
  const int wm = w >> 1, wn = w & 1;
  const int lrow = l & 15, lq = l >> 4;
  const int srow = tid >> 2, scol = (tid & 3) * 8;
  const ushort* Wb = w1T + (size_t)e * H_ * MH_ + (size_t)(nb * 128 + srow) * H_ + scol;
  char* AsB = (char*)As + w * 1024;
  char* BsB = (char*)Bs + w * 1024;
  for (int base = cx * 64; base < cnt; base += 64 * 8) {
    int sl = base + srow; if (sl > cnt - 1) sl = cnt - 1;
    const ushort* Ab = x + (size_t)slot_row[off + sl] * H_ + scol;
    f32x4 acc[2][4] = {};
    for (int k0 = 0; k0 < H_; k0 += 32) {
      async16(AsB,        Ab + k0);
      async16(BsB,        Wb + k0);
      async16(BsB + 4096, Wb + (size_t)64 * H_ + k0);
      __syncthreads();
      bf16x8 af[2], bfr[4];
#pragma unroll
      for (int i = 0; i < 2; i++)
        af[i] = *(const bf16x8*)(As + (wm * 32 + i * 16 + lrow) * 32 + lq * 8);
#pragma unroll
      for (int i = 0; i < 4; i++)
        bfr[i] = *(const bf16x8*)(Bs + (wn * 64 + i * 16 + lrow) * 32 + lq * 8);
#pragma unroll
      for (int mi = 0; mi < 2; mi++)
#pragma unroll
        for (int ni = 0; ni < 4; ni++)
          acc[mi][ni] = __builtin_amdgcn_mfma_f32_16x16x32_bf16(af[mi], bfr[ni], acc[mi][ni], 0, 0, 0);
      __syncthreads();
    }
    int mrem = cnt - base;
#pragma unroll
    for (int mi = 0; mi < 2; mi++)
#pragma unroll
      for (int ni = 0; ni < 4; ni++) {
        int col = nb * 128 + wn * 64 + ni * 16 + lrow;
        float bv = b1[e * MH_ + col];
#pragma unroll
        for (int r = 0; r < 4; r++) {
          int rl = wm * 32 + mi * 16 + lq * 4 + r;
          if (rl < mrem)
            hid[(size_t)(off + base + rl) * MH_ + col] = f2bf(fmaxf(acc[mi][ni][r] + bv, 0.f));
        }
      }
  }
}

// ---------------- expert GEMM2: x_moe[slot_row] += w * (hid @ e_w2[e] + b2) ----------------
__global__ __launch_bounds__(256)
void expert2_kernel(const ushort* __restrict__ hid, const ushort* __restrict__ w2T,
                    const float* __restrict__ b2, const int* __restrict__ counts,
                    const int* __restrict__ offsets, const int* __restrict__ slot_row,
                    const float* __restrict__ slot_w, float* __restrict__ xmoe) {
  const int e = blockIdx.z, nb = blockIdx.y, cx = blockIdx.x;
  const int cnt = counts[e];
  if (cnt == 0) return;
  const int off = offsets[e];
  __shared__ __align__(16) ushort As[64 * 32];
  __shared__ __align__(16) ushort Bs[128 * 32];
  const int tid = threadIdx.x;
  const int w = tid >> 6, l = tid & 63;
  const int wm = w >> 1, wn = w & 1;
  const int lrow = l & 15, lq = l >> 4;
  const int srow = tid >> 2, scol = (tid & 3) * 8;
  const ushort* Wb = w2T + (size_t)e * MH_ * H_ + (size_t)(nb * 128 + srow) * MH_ + scol;
  char* AsB = (char*)As + w * 1024;
  char* BsB = (char*)Bs + w * 1024;
  for (int base = cx * 64; base < cnt; base += 64 * 8) {
    int sl = base + srow; if (sl > cnt - 1) sl = cnt - 1;
    const ushort* Ab = hid + (size_t)(off + sl) * MH_ + scol;
    f32x4 acc[2][4] = {};
    for (int k0 = 0; k0 < MH_; k0 += 32) {
      async16(AsB,        Ab + k0);
      async16(BsB,        Wb + k0);
      async16(BsB + 4096, Wb + (size_t)64 * MH_ + k0);
      __syncthreads();
      bf16x8 af[2], bfr[4];
#pragma unroll
      for (int i = 0; i < 2; i++)
        af[i] = *(const bf16x8*)(As + (wm * 32 + i * 16 + lrow) * 32 + lq * 8);
#pragma unroll
      for (int i = 0; i < 4; i++)
        bfr[i] = *(const bf16x8*)(Bs + (wn * 64 + i * 16 + lrow) * 32 + lq * 8);
#pragma unroll
      for (int mi = 0; mi < 2; mi++)
#pragma unroll
        for (int ni = 0; ni < 4; ni++)
          acc[mi][ni] = __builtin_amdgcn_mfma_f32_16x16x32_bf16(af[mi], bfr[ni], acc[mi][ni], 0, 0, 0);
      __syncthreads();
    }
    int mrem = cnt - base;
#pragma unroll
    for (int mi = 0; mi < 2; mi++)
#pragma unroll
      for (int ni = 0; ni < 4; ni++) {
        int col = nb * 128 + wn * 64 + ni * 16 + lrow;
        float bv = b2[e * H_ + col];
#pragma unroll
        for (int r = 0; r < 4; r++) {
          int rl = wm * 32 + mi * 16 + lq * 4 + r;
          if (rl < mrem) {
            int s = off + base + rl;
            atomicAdd(&xmoe[(size_t)slot_row[s] * H_ + col], slot_w[s] * (acc[mi][ni][r] + bv));
          }
        }
      }
  }
}

// ---------------- policy2: mu = tanh(relu(x_moe) @ p2_w + b), std_out ----------------
__global__ void policy2_kernel(const float* __restrict__ xm, const float* __restrict__ w,
                               const float* __restrict__ b, const float* __restrict__ stdp,
                               float* __restrict__ out) {
  int l = threadIdx.x & 63;
  int row = blockIdx.x * 4 + (threadIdx.x >> 6);
  const float* xr = xm + (size_t)row * H_;
  const float4* x4 = (const float4*)(xr + l * 8);
  float4 a0 = x4[0], a1 = x4[1];
  float v[8] = {a0.x, a0.y, a0.z, a0.w, a1.x, a1.y, a1.z, a1.w};
#pragma unroll
  for (int j = 0; j < 8; j++) v[j] = fmaxf(v[j], 0.f);
  float res[7];
#pragma unroll
  for (int a = 0; a < A_; a++) {
    float s = 0;
#pragma unroll
    for (int j = 0; j < 8; j++) s += v[j] * w[(size_t)(l * 8 + j) * A_ + a];
    for (int o = 32; o; o >>= 1) s += __shfl_down(s, o);
    res[a] = s;
  }
  if (l == 0) {
    float sv = stdp[0];
#pragma unroll
    for (int a = 0; a < A_; a++) {
      out[(size_t)row * A_ + a] = tanhf(res[a] + b[a]);
      out[(size_t)B_ * A_ + (size_t)row * A_ + a] = sv;
    }
  }
}

extern "C" void kernel_launch(void* const* d_in, const int* in_sizes, int n_in,
                              void* d_out, int out_size, void* d_ws, size_t ws_size,
                              hipStream_t stream) {
  const float* obs      = (const float*)d_in[0];
  const float* sensor   = (const float*)d_in[1];
  const float* stdp     = (const float*)d_in[2];
  const float* trunk_w  = (const float*)d_in[3];
  const float* trunk_b  = (const float*)d_in[4];
  const float* ln_g     = (const float*)d_in[5];
  const float* ln_b     = (const float*)d_in[6];
  const float* p1_w     = (const float*)d_in[7];
  const float* p1_b     = (const float*)d_in[8];
  const float* g_w1     = (const float*)d_in[9];
  const float* g_b1     = (const float*)d_in[10];
  const float* g_w2     = (const float*)d_in[11];
  const float* g_b2     = (const float*)d_in[12];
  const float* e_w1     = (const float*)d_in[13];
  const float* e_b1     = (const float*)d_in[14];
  const float* e_w2     = (const float*)d_in[15];
  const float* e_b2     = (const float*)d_in[16];
  const float* p2_w     = (const float*)d_in[17];
  const float* p2_b     = (const float*)d_in[18];
  float* out = (float*)d_out;

  char* ws = (char*)d_ws;
  size_t off = 0;
  auto alloc = [&](size_t bytes) -> char* {
    char* p = ws + off;
    off += (bytes + 255) & ~(size_t)255;
    return p;
  };
  ushort* obs_bf  = (ushort*)alloc((size_t)B_ * R_ * 2);          // 160.6 MB
  ushort* wT      = (ushort*)alloc((size_t)F_ * R_ * 2);          // 40.1 MB
  float*  partial = (float*) alloc((size_t)KSLICES * B_ * F_ * 4);// 29.4 MB
  ushort* xcat    = (ushort*)alloc((size_t)B_ * (F_ + S_) * 2);   // 2.4 MB
  ushort* p1T     = (ushort*)alloc((size_t)H_ * (F_ + S_) * 2);
  ushort* xbuf    = (ushort*)alloc((size_t)B_ * H_ * 2);
  ushort* g1T     = (ushort*)alloc((size_t)G_ * H_ * 2);
  ushort* tbuf    = (ushort*)alloc((size_t)B_ * G_ * 2);
  ushort* ew1T    = (ushort*)alloc((size_t)E_ * H_ * MH_ * 2);    // 16.8 MB
  ushort* ew2T    = (ushort*)alloc((size_t)E_ * MH_ * H_ * 2);    // 16.8 MB
  ushort* hid     = (ushort*)alloc(((size_t)B_ * 4 + 64) * MH_ * 2); // 8.4 MB
  float*  xmoe    = (float*) alloc((size_t)B_ * H_ * 4);          // 4.2 MB
  float*  gate_w  = (float*) alloc((size_t)B_ * 4 * 4);
  int*    gate_i  = (int*)   alloc((size_t)B_ * 4 * 4);
  int*    counts  = (int*)   alloc(E_ * 4);
  int*    offsets = (int*)   alloc(E_ * 4);
  int*    cursors = (int*)   alloc(E_ * 4);
  float*  density = (float*) alloc(E_ * 4);
  int*    slot_row= (int*)   alloc((size_t)B_ * 4 * 4);
  float*  slot_w  = (float*) alloc((size_t)B_ * 4 * 4);

  hipMemsetAsync(counts, 0, E_ * 4, stream);
  hipMemsetAsync(cursors, 0, E_ * 4, stream);
  hipMemsetAsync(density, 0, E_ * 4, stream);
  hipMemsetAsync(xmoe, 0, (size_t)B_ * H_ * 4, stream);

  // weight/input conversions
  convert_bf16_kernel<<<8192, 256, 0, stream>>>(obs, obs_bf, (long)B_ * R_ / 4);
  transpose_bf16_kernel<<<dim3(F_/32, R_/32, 1),  dim3(32, 8), 0, stream>>>(trunk_w, wT, R_, F_);
  transpose_bf16_kernel<<<dim3(H_/32, (F_+S_)/32, 1), dim3(32, 8), 0, stream>>>(p1_w, p1T, F_ + S_, H_);
  transpose_bf16_kernel<<<dim3(G_/32, H_/32, 1),  dim3(32, 8), 0, stream>>>(g_w1, g1T, H_, G_);
  transpose_bf16_kernel<<<dim3(MH_/32, H_/32, E_), dim3(32, 8), 0, stream>>>(e_w1, ew1T, H_, MH_);
  transpose_bf16_kernel<<<dim3(H_/32, MH_/32, E_), dim3(32, 8), 0, stream>>>(e_w2, ew2T, MH_, H_);

  // trunk
  gemm_trunk_kernel<<<dim3(64, KSLICES), 256, 0, stream>>>(obs_bf, wT, partial);
  reduce_ln_kernel<<<B_, 256, 0, stream>>>(partial, trunk_b, ln_g, ln_b, sensor, xcat);

  // policy1 + gate MLP
  gemm_brelu_kernel<<<16 * 4, 256, 0, stream>>>(xcat, p1T, p1_b, xbuf, F_ + S_, H_, 4);
  gemm_brelu_kernel<<<16 * 2, 256, 0, stream>>>(xbuf, g1T, g_b1, tbuf, H_, G_, 2);
  gate_topk_kernel<<<B_, 256, 0, stream>>>(tbuf, g_w2, g_b2, gate_w, gate_i, density, counts);
  scan_aux_kernel<<<1, 64, 0, stream>>>(counts, density, offsets, out + 2 * B_ * A_);
  fill_slots_kernel<<<8, 256, 0, stream>>>(gate_i, gate_w, offsets, cursors, slot_row, slot_w);

  // experts (top-4 only)
  expert1_kernel<<<dim3(8, 4, E_), 256, 0, stream>>>(xbuf, ew1T, e_b1, counts, offsets, slot_row, hid);
  expert2_kernel<<<dim3(8, 4, E_), 256, 0, stream>>>(hid, ew2T, e_b2, counts, offsets, slot_row, slot_w, xmoe);

  // policy2 + std
  policy2_kernel<<<B_ / 4, 256, 0, stream>>>(xmoe, p2_w, p2_b, stdp, out);
}

// Round 2
// 985.812 us; speedup vs baseline: 1.0405x; 1.0405x over previous
//
#include <hip/hip_runtime.h>
#include <stdint.h>

typedef __attribute__((ext_vector_type(4))) float f32x4;
typedef __attribute__((ext_vector_type(8))) __bf16 bf16x8;
typedef unsigned short u16;
typedef u16 u16x8 __attribute__((ext_vector_type(8)));

#define DEV __device__ __forceinline__

DEV u16 f2bf(float f) {
  union { float f; uint32_t u; } v; v.f = f;
  uint32_t u = v.u;
  return (u16)((u + 0x7FFFu + ((u >> 16) & 1u)) >> 16);  // RTNE
}
DEV float bf2f(u16 h) {
  union { uint32_t u; float f; } v; v.u = ((uint32_t)h) << 16;
  return v.f;
}
// async global->LDS, 16B per lane. LDS dest is wave-uniform base + lane*16.
DEV void async16(void* lds, const void* g) {
  __builtin_amdgcn_global_load_lds((const __attribute__((address_space(1))) void*)g,
                                   (__attribute__((address_space(3))) void*)lds, 16, 0, 0);
}

#define B_  2048
#define R_  39200
#define F_  512
#define S_  64
#define H_  512
#define G_  256
#define E_  32
#define MH_ 512
#define A_  7
#define KSLICES 35
#define KSLICE_LEN 1120   // 39200/35 = 35*32

// ---------------- transpose + convert: in [z][R][C] f32 -> out [z][C][R] bf16 ----------------
// 64x64 tiles, 256 threads. float4 reads, ushort4 writes, pad-65 LDS (2-way max conflicts).
__global__ void transpose_bf16_kernel(const float* __restrict__ in, ushort* __restrict__ out,
                                      int R, int C) {
  __shared__ float tile[64][65];
  size_t bo = (size_t)blockIdx.z * R * C;
  const float* inp = in + bo;
  ushort* outp = out + bo;
  int r0 = blockIdx.y * 64, c0 = blockIdx.x * 64;
  int tid = threadIdx.x;
  {
    int rl = tid >> 2, cl = (tid & 3) * 16;
    if (r0 + rl < R) {
      const float4* src = (const float4*)(inp + (size_t)(r0 + rl) * C + c0 + cl);
#pragma unroll
      for (int j = 0; j < 4; j++) {
        float4 v = src[j];
        tile[rl][cl + 4 * j + 0] = v.x;
        tile[rl][cl + 4 * j + 1] = v.y;
        tile[rl][cl + 4 * j + 2] = v.z;
        tile[rl][cl + 4 * j + 3] = v.w;
      }
    }
  }
  __syncthreads();
  {
    int cl = tid >> 2, rl = (tid & 3) * 16;
    ushort* dst = outp + (size_t)(c0 + cl) * R + r0 + rl;
#pragma unroll
    for (int j = 0; j < 4; j++) {
      int rr = rl + 4 * j;
      if (r0 + rr < R) {
        ushort4 o;
        o.x = f2bf(tile[rr + 0][cl]);
        o.y = f2bf(tile[rr + 1][cl]);
        o.z = f2bf(tile[rr + 2][cl]);
        o.w = f2bf(tile[rr + 3][cl]);
        *(ushort4*)(dst + 4 * j) = o;
      }
    }
  }
}

// ---------------- trunk GEMM: A[2048,39200] fp32 (converted in-flight) @ Bt[512,39200] bf16
// -> partials[slice][2048][512] f32. 128x128 tile, BK=32, 4 waves 2x2.
__global__ __launch_bounds__(256)
void gemm_trunk_kernel(const float* __restrict__ A, const ushort* __restrict__ Bt,
                       float* __restrict__ Cp) {
  __shared__ __align__(16) ushort As[128 * 32];
  __shared__ __align__(16) ushort Bs[128 * 32];
  const int tid = threadIdx.x;
  const int w = tid >> 6, l = tid & 63;
  const int wm = w >> 1, wn = w & 1;
  const int lrow = l & 15, lq = l >> 4;
  const int mb = blockIdx.x >> 2, nb = blockIdx.x & 3;
  const int ks = blockIdx.y * KSLICE_LEN;
  f32x4 acc[4][4] = {};
  // B staging (bf16, async direct-to-LDS)
  const int srow = tid >> 2, scol = (tid & 3) * 8;
  const ushort* Bb = Bt + (size_t)(nb * 128 + srow) * R_ + scol;
  char* BsB = (char*)Bs + w * 1024;
  // A staging (fp32 -> bf16 in-register)
  const int arow = tid >> 1, acol = (tid & 1) * 16;
  const float* Ap = A + (size_t)(mb * 128 + arow) * R_ + acol;
  ushort* AsW = As + arow * 32 + acol;
  for (int k0 = ks; k0 < ks + KSLICE_LEN; k0 += 32) {
    async16(BsB,        Bb + k0);
    async16(BsB + 4096, Bb + (size_t)64 * R_ + k0);
    const float4* av = (const float4*)(Ap + k0);
    float4 f0 = av[0], f1 = av[1], f2 = av[2], f3 = av[3];
    u16x8 p0, p1;
    p0[0]=f2bf(f0.x); p0[1]=f2bf(f0.y); p0[2]=f2bf(f0.z); p0[3]=f2bf(f0.w);
    p0[4]=f2bf(f1.x); p0[5]=f2bf(f1.y); p0[6]=f2bf(f1.z); p0[7]=f2bf(f1.w);
    p1[0]=f2bf(f2.x); p1[1]=f2bf(f2.y); p1[2]=f2bf(f2.z); p1[3]=f2bf(f2.w);
    p1[4]=f2bf(f3.x); p1[5]=f2bf(f3.y); p1[6]=f2bf(f3.z); p1[7]=f2bf(f3.w);
    *(u16x8*)AsW       = p0;
    *(u16x8*)(AsW + 8) = p1;
    __syncthreads();
    bf16x8 af[4], bfr[4];
#pragma unroll
    for (int i = 0; i < 4; i++)
      af[i] = *(const bf16x8*)(As + (wm * 64 + i * 16 + lrow) * 32 + lq * 8);
#pragma unroll
    for (int i = 0; i < 4; i++)
      bfr[i] = *(const bf16x8*)(Bs + (wn * 64 + i * 16 + lrow) * 32 + lq * 8);
#pragma unroll
    for (int mi = 0; mi < 4; mi++)
#pragma unroll
      for (int ni = 0; ni < 4; ni++)
        acc[mi][ni] = __builtin_amdgcn_mfma_f32_16x16x32_bf16(af[mi], bfr[ni], acc[mi][ni], 0, 0, 0);
    __syncthreads();
  }
  float* C = Cp + (size_t)blockIdx.y * B_ * F_;
#pragma unroll
  for (int mi = 0; mi < 4; mi++)
#pragma unroll
    for (int ni = 0; ni < 4; ni++) {
      int col = nb * 128 + wn * 64 + ni * 16 + lrow;
#pragma unroll
      for (int r = 0; r < 4; r++) {
        int row = mb * 128 + wm * 64 + mi * 16 + lq * 4 + r;
        C[(size_t)row * F_ + col] = acc[mi][ni][r];
      }
    }
}

// ---------------- 64x64-tile GEMM, A[M,K] bf16 @ Bt[N,K] bf16, bias+relu -> bf16 ----------------
__global__ __launch_bounds__(256)
void gemm64_brelu_kernel(const ushort* __restrict__ A, const ushort* __restrict__ Bt,
                         const float* __restrict__ bias, ushort* __restrict__ out,
                         int K, int N, int nTiles) {
  __shared__ __align__(16) ushort As[64 * 32];
  __shared__ __align__(16) ushort Bs[64 * 32];
  const int tid = threadIdx.x;
  const int w = tid >> 6, l = tid & 63;
  const int wm = w >> 1, wn = w & 1;
  const int lrow = l & 15, lq = l >> 4;
  const int mb = blockIdx.x / nTiles, nb = blockIdx.x % nTiles;
  f32x4 acc[2][2] = {};
  const int srow = tid >> 2, scol = (tid & 3) * 8;
  const ushort* Ab = A + (size_t)(mb * 64 + srow) * K + scol;
  const ushort* Bb = Bt + (size_t)(nb * 64 + srow) * K + scol;
  char* AsB = (char*)As + w * 1024;
  char* BsB = (char*)Bs + w * 1024;
  for (int k0 = 0; k0 < K; k0 += 32) {
    async16(AsB, Ab + k0);
    async16(BsB, Bb + k0);
    __syncthreads();
    bf16x8 af[2], bfr[2];
#pragma unroll
    for (int i = 0; i < 2; i++)
      af[i] = *(const bf16x8*)(As + (wm * 32 + i * 16 + lrow) * 32 + lq * 8);
#pragma unroll
    for (int i = 0; i < 2; i++)
      bfr[i] = *(const bf16x8*)(Bs + (wn * 32 + i * 16 + lrow) * 32 + lq * 8);
#pragma unroll
    for (int mi = 0; mi < 2; mi++)
#pragma unroll
      for (int ni = 0; ni < 2; ni++)
        acc[mi][ni] = __builtin_amdgcn_mfma_f32_16x16x32_bf16(af[mi], bfr[ni], acc[mi][ni], 0, 0, 0);
    __syncthreads();
  }
#pragma unroll
  for (int mi = 0; mi < 2; mi++)
#pragma unroll
    for (int ni = 0; ni < 2; ni++) {
      int col = nb * 64 + wn * 32 + ni * 16 + lrow;
      float bv = bias[col];
#pragma unroll
      for (int r = 0; r < 4; r++) {
        int row = mb * 64 + wm * 32 + mi * 16 + lq * 4 + r;
        out[(size_t)row * N + col] = f2bf(fmaxf(acc[mi][ni][r] + bv, 0.f));
      }
    }
}

// ---------------- reduce split-K partials + bias + LayerNorm + tanh + sensor concat ----------------
__global__ void reduce_ln_kernel(const float* __restrict__ Cp, const float* __restrict__ tb,
                                 const float* __restrict__ g, const float* __restrict__ bb,
                                 const float* __restrict__ sensor, ushort* __restrict__ xcat) {
  int row = blockIdx.x, tid = threadIdx.x;
  const float* base = Cp + (size_t)row * F_;
  float v0 = tb[tid], v1 = tb[tid + 256];
#pragma unroll
  for (int s = 0; s < KSLICES; s++) {
    v0 += base[(size_t)s * B_ * F_ + tid];
    v1 += base[(size_t)s * B_ * F_ + tid + 256];
  }
  float s1 = v0 + v1, s2 = v0 * v0 + v1 * v1;
  for (int o = 32; o; o >>= 1) { s1 += __shfl_down(s1, o); s2 += __shfl_down(s2, o); }
  __shared__ float r1[4], r2[4];
  __shared__ float mus, rss;
  if ((tid & 63) == 0) { r1[tid >> 6] = s1; r2[tid >> 6] = s2; }
  __syncthreads();
  if (tid == 0) {
    float a = r1[0] + r1[1] + r1[2] + r1[3];
    float q = r2[0] + r2[1] + r2[2] + r2[3];
    float mu = a * (1.0f / F_);
    float var = q * (1.0f / F_) - mu * mu;
    mus = mu; rss = rsqrtf(var + 1e-5f);
  }
  __syncthreads();
  float mu = mus, rs = rss;
  ushort* xr = xcat + (size_t)row * (F_ + S_);
  xr[tid]       = f2bf(tanhf((v0 - mu) * rs * g[tid] + bb[tid]));
  xr[tid + 256] = f2bf(tanhf((v1 - mu) * rs * g[tid + 256] + bb[tid + 256]));
  if (tid < S_) xr[F_ + tid] = f2bf(sensor[(size_t)row * S_ + tid]);
}

// ---------------- gate layer2 + softmax + top4 + counts/density atomics ----------------
__global__ void gate_topk_kernel(const ushort* __restrict__ tbuf, const float* __restrict__ w2,
                                 const float* __restrict__ b2, float* __restrict__ gate_w,
                                 int* __restrict__ gate_i, float* __restrict__ density,
                                 int* __restrict__ counts) {
  int row = blockIdx.x, tid = threadIdx.x;
  __shared__ float trs[G_];
  const ushort* tr = tbuf + (size_t)row * G_;
  if (tid < 64) {
    ushort4 v = ((const ushort4*)tr)[tid];
    trs[tid * 4 + 0] = bf2f(v.x);
    trs[tid * 4 + 1] = bf2f(v.y);
    trs[tid * 4 + 2] = bf2f(v.z);
    trs[tid * 4 + 3] = bf2f(v.w);
  }
  __syncthreads();
  int jj = tid >> 5, e = tid & 31;
  float s = 0;
  int k0 = jj * 32;
#pragma unroll
  for (int k = 0; k < 32; k++) s += trs[k0 + k] * w2[(size_t)(k0 + k) * E_ + e];
  __shared__ float part[8][32];
  part[jj][e] = s;
  __syncthreads();
  if (tid < 32) {
    float logit = b2[tid];
#pragma unroll
    for (int j = 0; j < 8; j++) logit += part[j][tid];
    float m = logit;
    for (int o = 16; o; o >>= 1) m = fmaxf(m, __shfl_xor(m, o));
    float p = expf(logit - m);
    float sum = p;
    for (int o = 16; o; o >>= 1) sum += __shfl_xor(sum, o);
    float prob = p / sum;
    bool sel = false;
    float tv[4]; int ti[4];
#pragma unroll
    for (int it = 0; it < 4; it++) {
      float c = sel ? -1.0f : prob;
      float mx = c;
      for (int o = 16; o; o >>= 1) mx = fmaxf(mx, __shfl_xor(mx, o));
      unsigned long long bal = __ballot(c == mx);
      int idx = __ffsll(bal) - 1;
      if (tid == idx) sel = true;
      tv[it] = mx; ti[it] = idx;
    }
    float wsum = tv[0] + tv[1] + tv[2] + tv[3];
#pragma unroll
    for (int it = 0; it < 4; it++)
      if (tid == it) { gate_w[row * 4 + it] = tv[it] / wsum; gate_i[row * 4 + it] = ti[it]; }
    atomicAdd(&density[tid], prob);
    if (sel) atomicAdd(&counts[tid], 1);
  }
}

// ---------------- exclusive scan of counts + aux loss ----------------
__global__ void scan_aux_kernel(const int* __restrict__ counts, const float* __restrict__ density,
                                int* __restrict__ offsets, float* __restrict__ aux_out) {
  if (threadIdx.x == 0) {
    int acc = 0; float a = 0;
    for (int e = 0; e < E_; e++) {
      offsets[e] = acc; acc += counts[e];
      a += (float)counts[e] * density[e];
    }
    aux_out[0] = (float)E_ * a / ((float)B_ * (float)B_);
  }
}

// ---------------- bucket rows by expert ----------------
__global__ void fill_slots_kernel(const int* __restrict__ gate_i, const float* __restrict__ gate_w,
                                  const int* __restrict__ offsets, int* __restrict__ cursors,
                                  int* __restrict__ slot_row, float* __restrict__ slot_w) {
  int r = blockIdx.x * blockDim.x + threadIdx.x;
  if (r >= B_) return;
  for (int k = 0; k < 4; k++) {
    int e = gate_i[r * 4 + k];
    int pos = atomicAdd(&cursors[e], 1);
    int s = offsets[e] + pos;
    slot_row[s] = r;
    slot_w[s] = gate_w[r * 4 + k];
  }
}

// ---------------- expert GEMM1: hid = relu(x[slot_row] @ e_w1[e] + b1) ----------------
__global__ __launch_bounds__(256)
void expert1_kernel(const ushort* __restrict__ x, const ushort* __restrict__ w1T,
                    const float* __restrict__ b1, const int* __restrict__ counts,
                    const int* __restrict__ offsets, const int* __restrict__ slot_row,
                    ushort* __restrict__ hid) {
  const int e = blockIdx.z, nb = blockIdx.y, cx = blockIdx.x;
  const int cnt = counts[e];
  if (cnt == 0) return;
  const int off = offsets[e];
  __shared__ __align__(16) ushort As[64 * 32];
  __shared__ __align__(16) ushort Bs[128 * 32];
  const int tid = threadIdx.x;
  const int w = tid >> 6, l = tid & 63;
  const int wm = w >> 1, wn = w & 1;
  const int lrow = l & 15, lq = l >> 4;
  const int srow = tid >> 2, scol = (tid & 3) * 8;
  const ushort* Wb = w1T + (size_t)e * H_ * MH_ + (size_t)(nb * 128 + srow) * H_ + scol;
  char* AsB = (char*)As + w * 1024;
  char* BsB = (char*)Bs + w * 1024;
  for (int base = cx * 64; base < cnt; base += 64 * 8) {
    int sl = base + srow; if (sl > cnt - 1) sl = cnt - 1;
    const ushort* Ab = x + (size_t)slot_row[off + sl] * H_ + scol;
    f32x4 acc[2][4] = {};
    for (int k0 = 0; k0 < H_; k0 += 32) {
      async16(AsB,        Ab + k0);
      async16(BsB,        Wb + k0);
      async16(BsB + 4096, Wb + (size_t)64 * H_ + k0);
      __syncthreads();
      bf16x8 af[2], bfr[4];
#pragma unroll
      for (int i = 0; i < 2; i++)
        af[i] = *(const bf16x8*)(As + (wm * 32 + i * 16 + lrow) * 32 + lq * 8);
#pragma unroll
      for (int i = 0; i < 4; i++)
        bfr[i] = *(const bf16x8*)(Bs + (wn * 64 + i * 16 + lrow) * 32 + lq * 8);
#pragma unroll
      for (int mi = 0; mi < 2; mi++)
#pragma unroll
        for (int ni = 0; ni < 4; ni++)
          acc[mi][ni] = __builtin_amdgcn_mfma_f32_16x16x32_bf16(af[mi], bfr[ni], acc[mi][ni], 0, 0, 0);
      __syncthreads();
    }
    int mrem = cnt - base;
#pragma unroll
    for (int mi = 0; mi < 2; mi++)
#pragma unroll
      for (int ni = 0; ni < 4; ni++) {
        int col = nb * 128 + wn * 64 + ni * 16 + lrow;
        float bv = b1[e * MH_ + col];
#pragma unroll
        for (int r = 0; r < 4; r++) {
          int rl = wm * 32 + mi * 16 + lq * 4 + r;
          if (rl < mrem)
            hid[(size_t)(off + base + rl) * MH_ + col] = f2bf(fmaxf(acc[mi][ni][r] + bv, 0.f));
        }
      }
  }
}

// ---------------- expert GEMM2: x_moe[slot_row] += w * (hid @ e_w2[e] + b2) ----------------
__global__ __launch_bounds__(256)
void expert2_kernel(const ushort* __restrict__ hid, const ushort* __restrict__ w2T,
                    const float* __restrict__ b2, const int* __restrict__ counts,
                    const int* __restrict__ offsets, const int* __restrict__ slot_row,
                    const float* __restrict__ slot_w, float* __restrict__ xmoe) {
  const int e = blockIdx.z, nb = blockIdx.y, cx = blockIdx.x;
  const int cnt = counts[e];
  if (cnt == 0) return;
  const int off = offsets[e];
  __shared__ __align__(16) ushort As[64 * 32];
  __shared__ __align__(16) ushort Bs[128 * 32];
  const int tid = threadIdx.x;
  const int w = tid >> 6, l = tid & 63;
  const int wm = w >> 1, wn = w & 1;
  const int lrow = l & 15, lq = l >> 4;
  const int srow = tid >> 2, scol = (tid & 3) * 8;
  const ushort* Wb = w2T + (size_t)e * MH_ * H_ + (size_t)(nb * 128 + srow) * MH_ + scol;
  char* AsB = (char*)As + w * 1024;
  char* BsB = (char*)Bs + w * 1024;
  for (int base = cx * 64; base < cnt; base += 64 * 8) {
    int sl = base + srow; if (sl > cnt - 1) sl = cnt - 1;
    const ushort* Ab = hid + (size_t)(off + sl) * MH_ + scol;
    f32x4 acc[2][4] = {};
    for (int k0 = 0; k0 < MH_; k0 += 32) {
      async16(AsB,        Ab + k0);
      async16(BsB,        Wb + k0);
      async16(BsB + 4096, Wb + (size_t)64 * MH_ + k0);
      __syncthreads();
      bf16x8 af[2], bfr[4];
#pragma unroll
      for (int i = 0; i < 2; i++)
        af[i] = *(const bf16x8*)(As + (wm * 32 + i * 16 + lrow) * 32 + lq * 8);
#pragma unroll
      for (int i = 0; i < 4; i++)
        bfr[i] = *(const bf16x8*)(Bs + (wn * 64 + i * 16 + lrow) * 32 + lq * 8);
#pragma unroll
      for (int mi = 0; mi < 2; mi++)
#pragma unroll
        for (int ni = 0; ni < 4; ni++)
          acc[mi][ni] = __builtin_amdgcn_mfma_f32_16x16x32_bf16(af[mi], bfr[ni], acc[mi][ni], 0, 0, 0);
      __syncthreads();
    }
    int mrem = cnt - base;
#pragma unroll
    for (int mi = 0; mi < 2; mi++)
#pragma unroll
      for (int ni = 0; ni < 4; ni++) {
        int col = nb * 128 + wn * 64 + ni * 16 + lrow;
        float bv = b2[e * H_ + col];
#pragma unroll
        for (int r = 0; r < 4; r++) {
          int rl = wm * 32 + mi * 16 + lq * 4 + r;
          if (rl < mrem) {
            int s = off + base + rl;
            atomicAdd(&xmoe[(size_t)slot_row[s] * H_ + col], slot_w[s] * (acc[mi][ni][r] + bv));
          }
        }
      }
  }
}

// ---------------- policy2: mu = tanh(relu(x_moe) @ p2_w + b), std_out ----------------
__global__ void policy2_kernel(const float* __restrict__ xm, const float* __restrict__ w,
                               const float* __restrict__ b, const float* __restrict__ stdp,
                               float* __restrict__ out) {
  int l = threadIdx.x & 63;
  int row = blockIdx.x * 4 + (threadIdx.x >> 6);
  const float* xr = xm + (size_t)row * H_;
  const float4* x4 = (const float4*)(xr + l * 8);
  float4 a0 = x4[0], a1 = x4[1];
  float v[8] = {a0.x, a0.y, a0.z, a0.w, a1.x, a1.y, a1.z, a1.w};
#pragma unroll
  for (int j = 0; j < 8; j++) v[j] = fmaxf(v[j], 0.f);
  float res[7];
#pragma unroll
  for (int a = 0; a < A_; a++) {
    float s = 0;
#pragma unroll
    for (int j = 0; j < 8; j++) s += v[j] * w[(size_t)(l * 8 + j) * A_ + a];
    for (int o = 32; o; o >>= 1) s += __shfl_down(s, o);
    res[a] = s;
  }
  if (l == 0) {
    float sv = stdp[0];
#pragma unroll
    for (int a = 0; a < A_; a++) {
      out[(size_t)row * A_ + a] = tanhf(res[a] + b[a]);
      out[(size_t)B_ * A_ + (size_t)row * A_ + a] = sv;
    }
  }
}

extern "C" void kernel_launch(void* const* d_in, const int* in_sizes, int n_in,
                              void* d_out, int out_size, void* d_ws, size_t ws_size,
                              hipStream_t stream) {
  const float* obs      = (const float*)d_in[0];
  const float* sensor   = (const float*)d_in[1];
  const float* stdp     = (const float*)d_in[2];
  const float* trunk_w  = (const float*)d_in[3];
  const float* trunk_b  = (const float*)d_in[4];
  const float* ln_g     = (const float*)d_in[5];
  const float* ln_b     = (const float*)d_in[6];
  const float* p1_w     = (const float*)d_in[7];
  const float* p1_b     = (const float*)d_in[8];
  const float* g_w1     = (const float*)d_in[9];
  const float* g_b1     = (const float*)d_in[10];
  const float* g_w2     = (const float*)d_in[11];
  const float* g_b2     = (const float*)d_in[12];
  const float* e_w1     = (const float*)d_in[13];
  const float* e_b1     = (const float*)d_in[14];
  const float* e_w2     = (const float*)d_in[15];
  const float* e_b2     = (const float*)d_in[16];
  const float* p2_w     = (const float*)d_in[17];
  const float* p2_b     = (const float*)d_in[18];
  float* out = (float*)d_out;

  char* ws = (char*)d_ws;
  size_t off = 0;
  auto alloc = [&](size_t bytes) -> char* {
    char* p = ws + off;
    off += (bytes + 255) & ~(size_t)255;
    return p;
  };
  ushort* wT      = (ushort*)alloc((size_t)F_ * R_ * 2);            // 40.1 MB
  float*  partial = (float*) alloc((size_t)KSLICES * B_ * F_ * 4);  // 146.8 MB
  ushort* xcat    = (ushort*)alloc((size_t)B_ * (F_ + S_) * 2);
  ushort* p1T     = (ushort*)alloc((size_t)H_ * (F_ + S_) * 2);
  ushort* xbuf    = (ushort*)alloc((size_t)B_ * H_ * 2);
  ushort* g1T     = (ushort*)alloc((size_t)G_ * H_ * 2);
  ushort* tbuf    = (ushort*)alloc((size_t)B_ * G_ * 2);
  ushort* ew1T    = (ushort*)alloc((size_t)E_ * H_ * MH_ * 2);      // 16.8 MB
  ushort* ew2T    = (ushort*)alloc((size_t)E_ * MH_ * H_ * 2);      // 16.8 MB
  ushort* hid     = (ushort*)alloc(((size_t)B_ * 4 + 64) * MH_ * 2);
  float*  xmoe    = (float*) alloc((size_t)B_ * H_ * 4);
  float*  gate_w  = (float*) alloc((size_t)B_ * 4 * 4);
  int*    gate_i  = (int*)   alloc((size_t)B_ * 4 * 4);
  int*    counts  = (int*)   alloc(E_ * 4);
  int*    offsets = (int*)   alloc(E_ * 4);
  int*    cursors = (int*)   alloc(E_ * 4);
  float*  density = (float*) alloc(E_ * 4);
  int*    slot_row= (int*)   alloc((size_t)B_ * 4 * 4);
  float*  slot_w  = (float*) alloc((size_t)B_ * 4 * 4);

  hipMemsetAsync(counts, 0, E_ * 4, stream);
  hipMemsetAsync(cursors, 0, E_ * 4, stream);
  hipMemsetAsync(density, 0, E_ * 4, stream);
  hipMemsetAsync(xmoe, 0, (size_t)B_ * H_ * 4, stream);

  // weight transpose+convert (64x64 tiles)
  transpose_bf16_kernel<<<dim3(F_/64, (R_+63)/64, 1),   dim3(256), 0, stream>>>(trunk_w, wT, R_, F_);
  transpose_bf16_kernel<<<dim3(H_/64, (F_+S_)/64, 1),   dim3(256), 0, stream>>>(p1_w, p1T, F_ + S_, H_);
  transpose_bf16_kernel<<<dim3(G_/64, H_/64, 1),        dim3(256), 0, stream>>>(g_w1, g1T, H_, G_);
  transpose_bf16_kernel<<<dim3(MH_/64, H_/64, E_),      dim3(256), 0, stream>>>(e_w1, ew1T, H_, MH_);
  transpose_bf16_kernel<<<dim3(H_/64, MH_/64, E_),      dim3(256), 0, stream>>>(e_w2, ew2T, MH_, H_);

  // trunk (fp32 A staged in-flight; split-K = 35)
  gemm_trunk_kernel<<<dim3(64, KSLICES), 256, 0, stream>>>(obs, wT, partial);
  reduce_ln_kernel<<<B_, 256, 0, stream>>>(partial, trunk_b, ln_g, ln_b, sensor, xcat);

  // policy1 + gate MLP (64x64 tiles for block-count)
  gemm64_brelu_kernel<<<32 * 8, 256, 0, stream>>>(xcat, p1T, p1_b, xbuf, F_ + S_, H_, 8);
  gemm64_brelu_kernel<<<32 * 4, 256, 0, stream>>>(xbuf, g1T, g_b1, tbuf, H_, G_, 4);
  gate_topk_kernel<<<B_, 256, 0, stream>>>(tbuf, g_w2, g_b2, gate_w, gate_i, density, counts);
  scan_aux_kernel<<<1, 64, 0, stream>>>(counts, density, offsets, out + 2 * B_ * A_);
  fill_slots_kernel<<<8, 256, 0, stream>>>(gate_i, gate_w, offsets, cursors, slot_row, slot_w);

  // experts (top-4 only)
  expert1_kernel<<<dim3(8, 4, E_), 256, 0, stream>>>(xbuf, ew1T, e_b1, counts, offsets, slot_row, hid);
  expert2_kernel<<<dim3(8, 4, E_), 256, 0, stream>>>(hid, ew2T, e_b2, counts, offsets, slot_row, slot_w, xmoe);

  // policy2 + std
  policy2_kernel<<<B_ / 4, 256, 0, stream>>>(xmoe, p2_w, p2_b, stdp, out);
}

// Round 3
// 969.672 us; speedup vs baseline: 1.0578x; 1.0166x over previous
//
#include <hip/hip_runtime.h>
#include <stdint.h>

typedef __attribute__((ext_vector_type(4))) float f32x4;
typedef __attribute__((ext_vector_type(8))) __bf16 bf16x8;
typedef unsigned short u16;

#define DEV __device__ __forceinline__

DEV u16 f2bf(float f) {
  union { float f; uint32_t u; } v; v.f = f;
  uint32_t u = v.u;
  return (u16)((u + 0x7FFFu + ((u >> 16) & 1u)) >> 16);  // RTNE
}
DEV float bf2f(u16 h) {
  union { uint32_t u; float f; } v; v.u = ((uint32_t)h) << 16;
  return v.f;
}
// async global->LDS, 16B per lane. LDS dest = wave-uniform base + lane*16.
DEV void async16(void* lds, const void* g) {
  __builtin_amdgcn_global_load_lds((const __attribute__((address_space(1))) void*)g,
                                   (__attribute__((address_space(3))) void*)lds, 16, 0, 0);
}

#define B_  2048
#define R_  39200
#define F_  512
#define S_  64
#define H_  512
#define G_  256
#define E_  32
#define MH_ 512
#define A_  7
#define KSLICES 35
#define KSLICE_LEN 1120   // 39200/35 = 35*32

// ---------------- multi-transpose: 5 jobs, in [z][R][C] f32 -> out [z][C][R] bf16 ----------------
struct TJob { const float* in; ushort* out; int R, C, tilesX, tilesPerZ, off; };
struct TJobs { TJob j[5]; };

__global__ void multi_transpose_kernel(TJobs jobs) {
  __shared__ float tile[64][65];
  int bx = blockIdx.x;
  int ji = 0;
#pragma unroll
  for (int k = 1; k < 5; k++) if (bx >= jobs.j[k].off) ji = k;
  TJob jb = jobs.j[ji];
  int lin = bx - jb.off;
  int z = lin / jb.tilesPerZ;
  int rem = lin - z * jb.tilesPerZ;
  int tX = rem % jb.tilesX;
  int tY = rem / jb.tilesX;
  const float* inp = jb.in + (size_t)z * jb.R * jb.C;
  ushort* outp = jb.out + (size_t)z * jb.R * jb.C;
  int r0 = tY * 64, c0 = tX * 64;
  int R = jb.R, C = jb.C;
  int tid = threadIdx.x;
  {
    int rl = tid >> 2, cl = (tid & 3) * 16;
    if (r0 + rl < R) {
      const float4* src = (const float4*)(inp + (size_t)(r0 + rl) * C + c0 + cl);
#pragma unroll
      for (int j = 0; j < 4; j++) {
        float4 v = src[j];
        tile[rl][cl + 4 * j + 0] = v.x;
        tile[rl][cl + 4 * j + 1] = v.y;
        tile[rl][cl + 4 * j + 2] = v.z;
        tile[rl][cl + 4 * j + 3] = v.w;
      }
    }
  }
  __syncthreads();
  {
    int cl = tid >> 2, rl = (tid & 3) * 16;
    ushort* dst = outp + (size_t)(c0 + cl) * R + r0 + rl;
#pragma unroll
    for (int j = 0; j < 4; j++) {
      int rr = rl + 4 * j;
      if (r0 + rr < R) {
        ushort4 o;
        o.x = f2bf(tile[rr + 0][cl]);
        o.y = f2bf(tile[rr + 1][cl]);
        o.z = f2bf(tile[rr + 2][cl]);
        o.w = f2bf(tile[rr + 3][cl]);
        *(ushort4*)(dst + 4 * j) = o;
      }
    }
  }
}

// ---------------- trunk GEMM: A[2048,39200] fp32 (in-flight bf16) @ Bt[512,39200] bf16
// -> C[2048,512] f32 via atomic fp32 add. 128x256 tile, BK=32, 512 thr = 8 waves (2x4).
__global__ __launch_bounds__(512, 4)
void gemm_trunk_kernel(const float* __restrict__ A, const ushort* __restrict__ Bt,
                       float* __restrict__ C) {
  __shared__ __align__(16) ushort As[128 * 32];   // 8 KB
  __shared__ __align__(16) ushort Bs[256 * 32];   // 16 KB
  const int tid = threadIdx.x;
  const int w = tid >> 6, l = tid & 63;
  const int wm = w >> 2, wn = w & 3;              // 2 x 4 wave grid
  const int lrow = l & 15, lq = l >> 4;
  const int mb = blockIdx.x >> 1, nb = blockIdx.x & 1;
  const int ks = blockIdx.y * KSLICE_LEN;
  f32x4 acc[4][4] = {};
  // B staging: two async16 passes of 128 rows each
  const int srow = tid >> 2, scol = (tid & 3) * 8;
  const ushort* Bb0 = Bt + (size_t)(nb * 256 + srow) * R_ + scol;
  const ushort* Bb1 = Bb0 + (size_t)128 * R_;
  char* BsB = (char*)Bs + w * 1024;
  // A staging: 128x32 fp32 -> bf16, two float4 per thread
  const int ar = tid >> 3, ac = (tid & 7) * 4;
  const float* Ap0 = A + (size_t)(mb * 128 + ar) * R_ + ac;
  const float* Ap1 = Ap0 + (size_t)64 * R_;
  ushort* AsW0 = As + ar * 32 + ac;
  ushort* AsW1 = AsW0 + 64 * 32;
  for (int k0 = ks; k0 < ks + KSLICE_LEN; k0 += 32) {
    async16(BsB,        Bb0 + k0);
    async16(BsB + 8192, Bb1 + k0);
    float4 f0 = *(const float4*)(Ap0 + k0);
    float4 f1 = *(const float4*)(Ap1 + k0);
    ushort4 p0, p1;
    p0.x = f2bf(f0.x); p0.y = f2bf(f0.y); p0.z = f2bf(f0.z); p0.w = f2bf(f0.w);
    p1.x = f2bf(f1.x); p1.y = f2bf(f1.y); p1.z = f2bf(f1.z); p1.w = f2bf(f1.w);
    *(ushort4*)AsW0 = p0;
    *(ushort4*)AsW1 = p1;
    __syncthreads();
    bf16x8 af[4], bfr[4];
#pragma unroll
    for (int i = 0; i < 4; i++)
      af[i] = *(const bf16x8*)(As + (wm * 64 + i * 16 + lrow) * 32 + lq * 8);
#pragma unroll
    for (int i = 0; i < 4; i++)
      bfr[i] = *(const bf16x8*)(Bs + (wn * 64 + i * 16 + lrow) * 32 + lq * 8);
#pragma unroll
    for (int mi = 0; mi < 4; mi++)
#pragma unroll
      for (int ni = 0; ni < 4; ni++)
        acc[mi][ni] = __builtin_amdgcn_mfma_f32_16x16x32_bf16(af[mi], bfr[ni], acc[mi][ni], 0, 0, 0);
    __syncthreads();
  }
#pragma unroll
  for (int mi = 0; mi < 4; mi++)
#pragma unroll
    for (int ni = 0; ni < 4; ni++) {
      int col = nb * 256 + wn * 64 + ni * 16 + lrow;
#pragma unroll
      for (int r = 0; r < 4; r++) {
        int row = mb * 128 + wm * 64 + mi * 16 + lq * 4 + r;
        unsafeAtomicAdd(&C[(size_t)row * F_ + col], acc[mi][ni][r]);
      }
    }
}

// ---------------- bias + LayerNorm + tanh + sensor concat (reads atomic-accumulated C) ----------
__global__ void ln_kernel(const float* __restrict__ C, const float* __restrict__ tb,
                          const float* __restrict__ g, const float* __restrict__ bb,
                          const float* __restrict__ sensor, ushort* __restrict__ xcat) {
  int row = blockIdx.x, tid = threadIdx.x;
  float v0 = C[(size_t)row * F_ + tid] + tb[tid];
  float v1 = C[(size_t)row * F_ + tid + 256] + tb[tid + 256];
  float s1 = v0 + v1, s2 = v0 * v0 + v1 * v1;
  for (int o = 32; o; o >>= 1) { s1 += __shfl_down(s1, o); s2 += __shfl_down(s2, o); }
  __shared__ float r1[4], r2[4];
  __shared__ float mus, rss;
  if ((tid & 63) == 0) { r1[tid >> 6] = s1; r2[tid >> 6] = s2; }
  __syncthreads();
  if (tid == 0) {
    float a = r1[0] + r1[1] + r1[2] + r1[3];
    float q = r2[0] + r2[1] + r2[2] + r2[3];
    float mu = a * (1.0f / F_);
    float var = q * (1.0f / F_) - mu * mu;
    mus = mu; rss = rsqrtf(var + 1e-5f);
  }
  __syncthreads();
  float mu = mus, rs = rss;
  ushort* xr = xcat + (size_t)row * (F_ + S_);
  xr[tid]       = f2bf(tanhf((v0 - mu) * rs * g[tid] + bb[tid]));
  xr[tid + 256] = f2bf(tanhf((v1 - mu) * rs * g[tid + 256] + bb[tid + 256]));
  if (tid < S_) xr[F_ + tid] = f2bf(sensor[(size_t)row * S_ + tid]);
}

// ---------------- 64x64-tile GEMM, A[M,K] bf16 @ Bt[N,K] bf16, bias+relu -> bf16 ----------------
__global__ __launch_bounds__(256)
void gemm64_brelu_kernel(const ushort* __restrict__ A, const ushort* __restrict__ Bt,
                         const float* __restrict__ bias, ushort* __restrict__ out,
                         int K, int N, int nTiles) {
  __shared__ __align__(16) ushort As[64 * 32];
  __shared__ __align__(16) ushort Bs[64 * 32];
  const int tid = threadIdx.x;
  const int w = tid >> 6, l = tid & 63;
  const int wm = w >> 1, wn = w & 1;
  const int lrow = l & 15, lq = l >> 4;
  const int mb = blockIdx.x / nTiles, nb = blockIdx.x % nTiles;
  f32x4 acc[2][2] = {};
  const int srow = tid >> 2, scol = (tid & 3) * 8;
  const ushort* Ab = A + (size_t)(mb * 64 + srow) * K + scol;
  const ushort* Bb = Bt + (size_t)(nb * 64 + srow) * K + scol;
  char* AsB = (char*)As + w * 1024;
  char* BsB = (char*)Bs + w * 1024;
  for (int k0 = 0; k0 < K; k0 += 32) {
    async16(AsB, Ab + k0);
    async16(BsB, Bb + k0);
    __syncthreads();
    bf16x8 af[2], bfr[2];
#pragma unroll
    for (int i = 0; i < 2; i++)
      af[i] = *(const bf16x8*)(As + (wm * 32 + i * 16 + lrow) * 32 + lq * 8);
#pragma unroll
    for (int i = 0; i < 2; i++)
      bfr[i] = *(const bf16x8*)(Bs + (wn * 32 + i * 16 + lrow) * 32 + lq * 8);
#pragma unroll
    for (int mi = 0; mi < 2; mi++)
#pragma unroll
      for (int ni = 0; ni < 2; ni++)
        acc[mi][ni] = __builtin_amdgcn_mfma_f32_16x16x32_bf16(af[mi], bfr[ni], acc[mi][ni], 0, 0, 0);
    __syncthreads();
  }
#pragma unroll
  for (int mi = 0; mi < 2; mi++)
#pragma unroll
    for (int ni = 0; ni < 2; ni++) {
      int col = nb * 64 + wn * 32 + ni * 16 + lrow;
      float bv = bias[col];
#pragma unroll
      for (int r = 0; r < 4; r++) {
        int row = mb * 64 + wm * 32 + mi * 16 + lq * 4 + r;
        out[(size_t)row * N + col] = f2bf(fmaxf(acc[mi][ni][r] + bv, 0.f));
      }
    }
}

// ---------------- gate layer2 + softmax + top4 + counts/density atomics ----------------
__global__ void gate_topk_kernel(const ushort* __restrict__ tbuf, const float* __restrict__ w2,
                                 const float* __restrict__ b2, float* __restrict__ gate_w,
                                 int* __restrict__ gate_i, float* __restrict__ density,
                                 int* __restrict__ counts) {
  int row = blockIdx.x, tid = threadIdx.x;
  __shared__ float trs[G_];
  const ushort* tr = tbuf + (size_t)row * G_;
  if (tid < 64) {
    ushort4 v = ((const ushort4*)tr)[tid];
    trs[tid * 4 + 0] = bf2f(v.x);
    trs[tid * 4 + 1] = bf2f(v.y);
    trs[tid * 4 + 2] = bf2f(v.z);
    trs[tid * 4 + 3] = bf2f(v.w);
  }
  __syncthreads();
  int jj = tid >> 5, e = tid & 31;
  float s = 0;
  int k0 = jj * 32;
#pragma unroll
  for (int k = 0; k < 32; k++) s += trs[k0 + k] * w2[(size_t)(k0 + k) * E_ + e];
  __shared__ float part[8][32];
  part[jj][e] = s;
  __syncthreads();
  if (tid < 32) {
    float logit = b2[tid];
#pragma unroll
    for (int j = 0; j < 8; j++) logit += part[j][tid];
    float m = logit;
    for (int o = 16; o; o >>= 1) m = fmaxf(m, __shfl_xor(m, o));
    float p = expf(logit - m);
    float sum = p;
    for (int o = 16; o; o >>= 1) sum += __shfl_xor(sum, o);
    float prob = p / sum;
    bool sel = false;
    float tv[4]; int ti[4];
#pragma unroll
    for (int it = 0; it < 4; it++) {
      float c = sel ? -1.0f : prob;
      float mx = c;
      for (int o = 16; o; o >>= 1) mx = fmaxf(mx, __shfl_xor(mx, o));
      unsigned long long bal = __ballot(c == mx);
      int idx = __ffsll(bal) - 1;
      if (tid == idx) sel = true;
      tv[it] = mx; ti[it] = idx;
    }
    float wsum = tv[0] + tv[1] + tv[2] + tv[3];
#pragma unroll
    for (int it = 0; it < 4; it++)
      if (tid == it) { gate_w[row * 4 + it] = tv[it] / wsum; gate_i[row * 4 + it] = ti[it]; }
    atomicAdd(&density[tid], prob);
    if (sel) atomicAdd(&counts[tid], 1);
  }
}

// ---------------- scan counts + aux loss + bucket rows (single block) ----------------
__global__ void scan_fill_kernel(const int* __restrict__ counts, const float* __restrict__ density,
                                 const int* __restrict__ gate_i, const float* __restrict__ gate_w,
                                 int* __restrict__ offsets, int* __restrict__ slot_row,
                                 float* __restrict__ slot_w, float* __restrict__ aux_out) {
  __shared__ int soff[E_];
  __shared__ int scur[E_];
  int tid = threadIdx.x;
  if (tid < E_) scur[tid] = 0;
  if (tid == 0) {
    int acc = 0; float a = 0;
    for (int e = 0; e < E_; e++) {
      soff[e] = acc; offsets[e] = acc; acc += counts[e];
      a += (float)counts[e] * density[e];
    }
    aux_out[0] = (float)E_ * a / ((float)B_ * (float)B_);
  }
  __syncthreads();
  for (int r = tid; r < B_; r += blockDim.x) {
#pragma unroll
    for (int k = 0; k < 4; k++) {
      int e = gate_i[r * 4 + k];
      int pos = atomicAdd(&scur[e], 1);
      int s = soff[e] + pos;
      slot_row[s] = r;
      slot_w[s] = gate_w[r * 4 + k];
    }
  }
}

// ---------------- expert GEMM1: hid = relu(x[slot_row] @ e_w1[e] + b1) ----------------
__global__ __launch_bounds__(256)
void expert1_kernel(const ushort* __restrict__ x, const ushort* __restrict__ w1T,
                    const float* __restrict__ b1, const int* __restrict__ counts,
                    const int* __restrict__ offsets, const int* __restrict__ slot_row,
                    ushort* __restrict__ hid) {
  const int e = blockIdx.z, nb = blockIdx.y, cx = blockIdx.x;
  const int cnt = counts[e];
  if (cnt == 0) return;
  const int off = offsets[e];
  __shared__ __align__(16) ushort As[64 * 32];
  __shared__ __align__(16) ushort Bs[128 * 32];
  const int tid = threadIdx.x;
  const int w = tid >> 6, l = tid & 63;
  const int wm = w >> 1, wn = w & 1;
  const int lrow = l & 15, lq = l >> 4;
  const int srow = tid >> 2, scol = (tid & 3) * 8;
  const ushort* Wb = w1T + (size_t)e * H_ * MH_ + (size_t)(nb * 128 + srow) * H_ + scol;
  char* AsB = (char*)As + w * 1024;
  char* BsB = (char*)Bs + w * 1024;
  for (int base = cx * 64; base < cnt; base += 64 * 8) {
    int sl = base + srow; if (sl > cnt - 1) sl = cnt - 1;
    const ushort* Ab = x + (size_t)slot_row[off + sl] * H_ + scol;
    f32x4 acc[2][4] = {};
    for (int k0 = 0; k0 < H_; k0 += 32) {
      async16(AsB,        Ab + k0);
      async16(BsB,        Wb + k0);
      async16(BsB + 4096, Wb + (size_t)64 * H_ + k0);
      __syncthreads();
      bf16x8 af[2], bfr[4];
#pragma unroll
      for (int i = 0; i < 2; i++)
        af[i] = *(const bf16x8*)(As + (wm * 32 + i * 16 + lrow) * 32 + lq * 8);
#pragma unroll
      for (int i = 0; i < 4; i++)
        bfr[i] = *(const bf16x8*)(Bs + (wn * 64 + i * 16 + lrow) * 32 + lq * 8);
#pragma unroll
      for (int mi = 0; mi < 2; mi++)
#pragma unroll
        for (int ni = 0; ni < 4; ni++)
          acc[mi][ni] = __builtin_amdgcn_mfma_f32_16x16x32_bf16(af[mi], bfr[ni], acc[mi][ni], 0, 0, 0);
      __syncthreads();
    }
    int mrem = cnt - base;
#pragma unroll
    for (int mi = 0; mi < 2; mi++)
#pragma unroll
      for (int ni = 0; ni < 4; ni++) {
        int col = nb * 128 + wn * 64 + ni * 16 + lrow;
        float bv = b1[e * MH_ + col];
#pragma unroll
        for (int r = 0; r < 4; r++) {
          int rl = wm * 32 + mi * 16 + lq * 4 + r;
          if (rl < mrem)
            hid[(size_t)(off + base + rl) * MH_ + col] = f2bf(fmaxf(acc[mi][ni][r] + bv, 0.f));
        }
      }
  }
}

// ---------------- expert GEMM2: x_moe[slot_row] += w * (hid @ e_w2[e] + b2) ----------------
__global__ __launch_bounds__(256)
void expert2_kernel(const ushort* __restrict__ hid, const ushort* __restrict__ w2T,
                    const float* __restrict__ b2, const int* __restrict__ counts,
                    const int* __restrict__ offsets, const int* __restrict__ slot_row,
                    const float* __restrict__ slot_w, float* __restrict__ xmoe) {
  const int e = blockIdx.z, nb = blockIdx.y, cx = blockIdx.x;
  const int cnt = counts[e];
  if (cnt == 0) return;
  const int off = offsets[e];
  __shared__ __align__(16) ushort As[64 * 32];
  __shared__ __align__(16) ushort Bs[128 * 32];
  const int tid = threadIdx.x;
  const int w = tid >> 6, l = tid & 63;
  const int wm = w >> 1, wn = w & 1;
  const int lrow = l & 15, lq = l >> 4;
  const int srow = tid >> 2, scol = (tid & 3) * 8;
  const ushort* Wb = w2T + (size_t)e * MH_ * H_ + (size_t)(nb * 128 + srow) * MH_ + scol;
  char* AsB = (char*)As + w * 1024;
  char* BsB = (char*)Bs + w * 1024;
  for (int base = cx * 64; base < cnt; base += 64 * 8) {
    int sl = base + srow; if (sl > cnt - 1) sl = cnt - 1;
    const ushort* Ab = hid + (size_t)(off + sl) * MH_ + scol;
    f32x4 acc[2][4] = {};
    for (int k0 = 0; k0 < MH_; k0 += 32) {
      async16(AsB,        Ab + k0);
      async16(BsB,        Wb + k0);
      async16(BsB + 4096, Wb + (size_t)64 * MH_ + k0);
      __syncthreads();
      bf16x8 af[2], bfr[4];
#pragma unroll
      for (int i = 0; i < 2; i++)
        af[i] = *(const bf16x8*)(As + (wm * 32 + i * 16 + lrow) * 32 + lq * 8);
#pragma unroll
      for (int i = 0; i < 4; i++)
        bfr[i] = *(const bf16x8*)(Bs + (wn * 64 + i * 16 + lrow) * 32 + lq * 8);
#pragma unroll
      for (int mi = 0; mi < 2; mi++)
#pragma unroll
        for (int ni = 0; ni < 4; ni++)
          acc[mi][ni] = __builtin_amdgcn_mfma_f32_16x16x32_bf16(af[mi], bfr[ni], acc[mi][ni], 0, 0, 0);
      __syncthreads();
    }
    int mrem = cnt - base;
#pragma unroll
    for (int mi = 0; mi < 2; mi++)
#pragma unroll
      for (int ni = 0; ni < 4; ni++) {
        int col = nb * 128 + wn * 64 + ni * 16 + lrow;
        float bv = b2[e * H_ + col];
#pragma unroll
        for (int r = 0; r < 4; r++) {
          int rl = wm * 32 + mi * 16 + lq * 4 + r;
          if (rl < mrem) {
            int s = off + base + rl;
            unsafeAtomicAdd(&xmoe[(size_t)slot_row[s] * H_ + col], slot_w[s] * (acc[mi][ni][r] + bv));
          }
        }
      }
  }
}

// ---------------- policy2: mu = tanh(relu(x_moe) @ p2_w + b), std_out ----------------
__global__ void policy2_kernel(const float* __restrict__ xm, const float* __restrict__ w,
                               const float* __restrict__ b, const float* __restrict__ stdp,
                               float* __restrict__ out) {
  int l = threadIdx.x & 63;
  int row = blockIdx.x * 4 + (threadIdx.x >> 6);
  const float* xr = xm + (size_t)row * H_;
  const float4* x4 = (const float4*)(xr + l * 8);
  float4 a0 = x4[0], a1 = x4[1];
  float v[8] = {a0.x, a0.y, a0.z, a0.w, a1.x, a1.y, a1.z, a1.w};
#pragma unroll
  for (int j = 0; j < 8; j++) v[j] = fmaxf(v[j], 0.f);
  float res[7];
#pragma unroll
  for (int a = 0; a < A_; a++) {
    float s = 0;
#pragma unroll
    for (int j = 0; j < 8; j++) s += v[j] * w[(size_t)(l * 8 + j) * A_ + a];
    for (int o = 32; o; o >>= 1) s += __shfl_down(s, o);
    res[a] = s;
  }
  if (l == 0) {
    float sv = stdp[0];
#pragma unroll
    for (int a = 0; a < A_; a++) {
      out[(size_t)row * A_ + a] = tanhf(res[a] + b[a]);
      out[(size_t)B_ * A_ + (size_t)row * A_ + a] = sv;
    }
  }
}

extern "C" void kernel_launch(void* const* d_in, const int* in_sizes, int n_in,
                              void* d_out, int out_size, void* d_ws, size_t ws_size,
                              hipStream_t stream) {
  const float* obs      = (const float*)d_in[0];
  const float* sensor   = (const float*)d_in[1];
  const float* stdp     = (const float*)d_in[2];
  const float* trunk_w  = (const float*)d_in[3];
  const float* trunk_b  = (const float*)d_in[4];
  const float* ln_g     = (const float*)d_in[5];
  const float* ln_b     = (const float*)d_in[6];
  const float* p1_w     = (const float*)d_in[7];
  const float* p1_b     = (const float*)d_in[8];
  const float* g_w1     = (const float*)d_in[9];
  const float* g_b1     = (const float*)d_in[10];
  const float* g_w2     = (const float*)d_in[11];
  const float* g_b2     = (const float*)d_in[12];
  const float* e_w1     = (const float*)d_in[13];
  const float* e_b1     = (const float*)d_in[14];
  const float* e_w2     = (const float*)d_in[15];
  const float* e_b2     = (const float*)d_in[16];
  const float* p2_w     = (const float*)d_in[17];
  const float* p2_b     = (const float*)d_in[18];
  float* out = (float*)d_out;

  char* ws = (char*)d_ws;
  size_t off = 0;
  auto alloc = [&](size_t bytes) -> char* {
    char* p = ws + off;
    off += (bytes + 255) & ~(size_t)255;
    return p;
  };
  ushort* wT      = (ushort*)alloc((size_t)F_ * R_ * 2);            // 40.1 MB
  float*  Cbuf    = (float*) alloc((size_t)B_ * F_ * 4);            // 4.2 MB   (zeroed, adjacent w/ xmoe)
  float*  xmoe    = (float*) alloc((size_t)B_ * H_ * 4);            // 4.2 MB
  ushort* xcat    = (ushort*)alloc((size_t)B_ * (F_ + S_) * 2);
  ushort* p1T     = (ushort*)alloc((size_t)H_ * (F_ + S_) * 2);
  ushort* xbuf    = (ushort*)alloc((size_t)B_ * H_ * 2);
  ushort* g1T     = (ushort*)alloc((size_t)G_ * H_ * 2);
  ushort* tbuf    = (ushort*)alloc((size_t)B_ * G_ * 2);
  ushort* ew1T    = (ushort*)alloc((size_t)E_ * H_ * MH_ * 2);      // 16.8 MB
  ushort* ew2T    = (ushort*)alloc((size_t)E_ * MH_ * H_ * 2);      // 16.8 MB
  ushort* hid     = (ushort*)alloc(((size_t)B_ * 4 + 64) * MH_ * 2);
  int*    counts  = (int*)   alloc(E_ * 4);                          // adjacent: one memset
  float*  density = (float*) alloc(E_ * 4);
  int*    offsets = (int*)   alloc(E_ * 4);
  float*  gate_w  = (float*) alloc((size_t)B_ * 4 * 4);
  int*    gate_i  = (int*)   alloc((size_t)B_ * 4 * 4);
  int*    slot_row= (int*)   alloc((size_t)B_ * 4 * 4);
  float*  slot_w  = (float*) alloc((size_t)B_ * 4 * 4);

  hipMemsetAsync(counts, 0, 512, stream);                            // counts + density
  hipMemsetAsync(Cbuf, 0, (size_t)(B_ * F_ + B_ * H_) * 4, stream);  // Cbuf + xmoe

  // single transpose+convert pass for all 5 weight matrices
  TJobs jobs;
  jobs.j[0] = { trunk_w, wT,   R_,      F_, F_ / 64,      ((R_ + 63) / 64) * (F_ / 64), 0 };
  int o1 = jobs.j[0].tilesPerZ;
  jobs.j[1] = { p1_w,    p1T,  F_ + S_, H_, H_ / 64,      ((F_ + S_) / 64) * (H_ / 64), o1 };
  int o2 = o1 + jobs.j[1].tilesPerZ;
  jobs.j[2] = { g_w1,    g1T,  H_,      G_, G_ / 64,      (H_ / 64) * (G_ / 64),        o2 };
  int o3 = o2 + jobs.j[2].tilesPerZ;
  jobs.j[3] = { e_w1,    ew1T, H_,      MH_, MH_ / 64,    (H_ / 64) * (MH_ / 64),       o3 };
  int o4 = o3 + E_ * jobs.j[3].tilesPerZ;
  jobs.j[4] = { e_w2,    ew2T, MH_,     H_, H_ / 64,      (MH_ / 64) * (H_ / 64),       o4 };
  int total = o4 + E_ * jobs.j[4].tilesPerZ;
  multi_transpose_kernel<<<total, 256, 0, stream>>>(jobs);

  // trunk (fp32 A in-flight convert; split-K via fp32 atomics into Cbuf)
  gemm_trunk_kernel<<<dim3(32, KSLICES), 512, 0, stream>>>(obs, wT, Cbuf);
  ln_kernel<<<B_, 256, 0, stream>>>(Cbuf, trunk_b, ln_g, ln_b, sensor, xcat);

  // policy1 + gate MLP
  gemm64_brelu_kernel<<<32 * 8, 256, 0, stream>>>(xcat, p1T, p1_b, xbuf, F_ + S_, H_, 8);
  gemm64_brelu_kernel<<<32 * 4, 256, 0, stream>>>(xbuf, g1T, g_b1, tbuf, H_, G_, 4);
  gate_topk_kernel<<<B_, 256, 0, stream>>>(tbuf, g_w2, g_b2, gate_w, gate_i, density, counts);
  scan_fill_kernel<<<1, 1024, 0, stream>>>(counts, density, gate_i, gate_w, offsets,
                                           slot_row, slot_w, out + 2 * B_ * A_);

  // experts (top-4 only)
  expert1_kernel<<<dim3(8, 4, E_), 256, 0, stream>>>(xbuf, ew1T, e_b1, counts, offsets, slot_row, hid);
  expert2_kernel<<<dim3(8, 4, E_), 256, 0, stream>>>(hid, ew2T, e_b2, counts, offsets, slot_row, slot_w, xmoe);

  // policy2 + std
  policy2_kernel<<<B_ / 4, 256, 0, stream>>>(xmoe, p2_w, p2_b, stdp, out);
}